// Round 7
// baseline (148.291 us; speedup 1.0000x reference)
//
#include <hip/hip_runtime.h>

typedef __attribute__((ext_vector_type(8))) __bf16 bf16x8;
typedef __attribute__((ext_vector_type(4))) float f32x4;
typedef unsigned long long u64;

#define KC 256             // k-floats per chunk: one row = 1KB = one wave-wide float4 instr
#define NCHUNK 8           // 2048 / 256
#define NSH 16             // dmat atomic shards
#define OFF_REC 65536      // float offset of per-t records, after dshard[16][4096]
#define RECSZ 8192         // per-t record: NN[4096] | AA[4096]

__device__ __forceinline__ unsigned short f2bf(float x) {
    unsigned u = __float_as_uint(x);
    u += 0x7FFFu + ((u >> 16) & 1u);   // round-to-nearest-even
    return (unsigned short)(u >> 16);
}

// grid 200 (one block per t) x 1024 threads (16 waves = 4/SIMD).
// Wave w owns 16x16 tile (it=w>>2, jt=w&3) of all 3 Grams.
// Double-buffered LDS, loads for c+1 issued before MFMA(c).
__global__ __launch_bounds__(1024, 4) void cl_main(const float* __restrict__ feats,
                                                   float* __restrict__ ws)
{
    const int t   = blockIdx.x;          // 0..199
    const int tid = threadIdx.x;         // 0..1023
    const int w   = tid >> 6;            // wave 0..15
    const int l   = tid & 63;
    const int r16 = tid & 15;
    const int kg  = (tid & 63) >> 4;
    const int it  = w >> 2, jt = w & 3;
    const int itb = it * 16, jtb = jt * 16;

    __shared__ __align__(16) unsigned short lds[2][128][KC];   // 128 KB
    __shared__ float n2s[64], a2s[64];

    const size_t kbase = (size_t)t * 2048;
    const int rs = (r16 & 7) << 3;       // frag-read swizzle (frag row & 7 == r16 & 7)

    f32x4 accD  = {0.f, 0.f, 0.f, 0.f};
    f32x4 accNN = {0.f, 0.f, 0.f, 0.f};
    f32x4 accAA = {0.f, 0.f, 0.f, 0.f};

    float4 vA[8], vB[8];   // two named staging sets (static indexing)

#define LOAD_CH(V, c)                                                       \
    {                                                                       \
        _Pragma("unroll")                                                   \
        for (int rr = 0; rr < 8; ++rr) {                                    \
            const int row = w*8 + rr;                                       \
            V[rr] = *(const float4*)(feats + (size_t)row * 409600 + kbase + (c)*KC + 4*l); \
        }                                                                   \
    }

#define WRITE_CH(V, buf)                                                    \
    {                                                                       \
        _Pragma("unroll")                                                   \
        for (int rr = 0; rr < 8; ++rr) {                                    \
            const int row = w*8 + rr;                                       \
            ushort4 p;                                                      \
            p.x = f2bf(V[rr].x); p.y = f2bf(V[rr].y);                       \
            p.z = f2bf(V[rr].z); p.w = f2bf(V[rr].w);                       \
            *(ushort4*)&lds[buf][row][(4*l) ^ (rr << 3)] = p;               \
        }                                                                   \
    }

#define MFMA_CH(buf)                                                        \
    {                                                                       \
        const unsigned short (*L)[KC] = lds[buf];                           \
        _Pragma("unroll")                                                   \
        for (int ks = 0; ks < 8; ++ks) {                                    \
            const int kb = (ks*32 + kg*8) ^ rs;                             \
            bf16x8 aN = *(const bf16x8*)&L[itb + r16][kb];                  \
            bf16x8 aA = *(const bf16x8*)&L[64 + itb + r16][kb];             \
            bf16x8 bN = *(const bf16x8*)&L[jtb + r16][kb];                  \
            bf16x8 bA = *(const bf16x8*)&L[64 + jtb + r16][kb];             \
            accD  = __builtin_amdgcn_mfma_f32_16x16x32_bf16(aN, bA, accD,  0, 0, 0); \
            accNN = __builtin_amdgcn_mfma_f32_16x16x32_bf16(aN, bN, accNN, 0, 0, 0); \
            accAA = __builtin_amdgcn_mfma_f32_16x16x32_bf16(aA, bA, accAA, 0, 0, 0); \
        }                                                                   \
    }

    // prologue: chunk 0 staged into buf0
    LOAD_CH(vA, 0)
    WRITE_CH(vA, 0)
    __syncthreads();

    #pragma unroll 1
    for (int cc = 0; cc < 4; ++cc) {
        const int c = 2*cc;
        LOAD_CH(vB, c + 1)               // in flight across MFMA(0)
        MFMA_CH(0)
        WRITE_CH(vB, 1)
        __syncthreads();
        if (c + 2 < NCHUNK) LOAD_CH(vA, c + 2)   // in flight across MFMA(1)
        MFMA_CH(1)
        if (c + 2 < NCHUNK) WRITE_CH(vA, 0)
        __syncthreads();
    }

    // n2/a2 from Gram diagonals (tiles with it==jt)
    if (it == jt && kg == (r16 >> 2)) {
        n2s[itb + r16] = accNN[r16 & 3];
        a2s[itb + r16] = accAA[r16 & 3];
    }
    __syncthreads();

    // epilogue: hinge -> sharded dmat atomics; NN/AA -> exclusive per-t record
    const int sh = (t & (NSH - 1)) * 4096;
    float* rec = ws + OFF_REC + (size_t)t * RECSZ;
    #pragma unroll
    for (int r = 0; r < 4; ++r) {
        const int i  = itb + kg*4 + r;
        const int j  = jtb + r16;
        const int ij = i*64 + j;
        float dist2 = fmaxf(n2s[i] + a2s[j] - 2.f * accD[r], 0.f);
        float v = fmaxf(200.f - sqrtf(dist2), 0.f);
        atomicAdd(&ws[sh + ij], v * v * 0.005f);   // 1/200
        rec[ij]        = accNN[r];
        rec[4096 + ij] = accAA[r];
    }
#undef LOAD_CH
#undef WRITE_CH
#undef MFMA_CH
}

__global__ __launch_bounds__(1024) void cl_final(const float* __restrict__ ws,
                                                 float* __restrict__ out)
{
    const int tid = threadIdx.x;
    __shared__ u64   wmin[16];
    __shared__ int   sIdx;
    __shared__ float sDmin;
    __shared__ float sG[16][64], sA[16][64], sRn[16][64], sRa[16][64];

    // argmin over shard-summed dmat, first-occurrence tie-break via packed key
    u64 best = ~0ull;
    #pragma unroll
    for (int u = 0; u < 4; ++u) {
        const int ij = u*1024 + tid;
        float s = 0.f;
        #pragma unroll
        for (int sh = 0; sh < NSH; ++sh) s += ws[sh*4096 + ij];
        u64 key = ((u64)__float_as_uint(s) << 12) | (unsigned)ij;   // s>=0: order-preserving
        best = key < best ? key : best;
    }
    #pragma unroll
    for (int off = 32; off > 0; off >>= 1) {
        u64 o = __shfl_xor(best, off);
        best = o < best ? o : best;
    }
    if ((tid & 63) == 0) wmin[tid >> 6] = best;
    __syncthreads();
    if (tid == 0) {
        u64 m = wmin[0];
        for (int k = 1; k < 16; ++k) m = wmin[k] < m ? wmin[k] : m;
        sIdx  = (int)(m & 0xFFF);
        sDmin = __uint_as_float((unsigned)(m >> 12));
    }
    __syncthreads();
    const int idx = sIdx;
    const int mn = idx >> 6;
    const int ma = idx & 63;

    // Gram columns at (mn, ma) + diagonals, summed over t (16 t-phases)
    const int g = tid >> 6;
    const int i = tid & 63;
    float gcn = 0.f, gca = 0.f, rn = 0.f, ra = 0.f;
    for (int t = g; t < 200; t += 16) {
        const float* rec = ws + OFF_REC + (size_t)t * RECSZ;
        gcn += rec[i*64 + mn];
        gca += rec[4096 + i*64 + ma];
        rn  += rec[i*65];          // NN diag -> Rn[i]
        ra  += rec[4096 + i*65];   // AA diag -> Ra[i]
    }
    sG[g][i] = gcn; sA[g][i] = gca; sRn[g][i] = rn; sRa[g][i] = ra;
    __syncthreads();

    if (tid < 64) {   // wave 0
        float fgn = 0.f, fga = 0.f, frn = 0.f, fra = 0.f;
        #pragma unroll
        for (int g2 = 0; g2 < 16; ++g2) {
            fgn += sG[g2][tid];  fga += sA[g2][tid];
            frn += sRn[g2][tid]; fra += sRa[g2][tid];
        }
        const float rnm = __shfl(frn, mn);
        const float ram = __shfl(fra, ma);
        float tn = (tid != mn) ? (frn + rnm - 2.f * fgn) : 0.f;
        float ta = (tid != ma) ? (fra + ram - 2.f * fga) : 0.f;
        float s = tn + ta;
        #pragma unroll
        for (int off = 32; off > 0; off >>= 1) s += __shfl_xor(s, off);
        if (tid == 0)
            out[0] = 0.001f * sDmin + s * (1.f / 12800.f);   // /(200*64)
    }
}

extern "C" void kernel_launch(void* const* d_in, const int* in_sizes, int n_in,
                              void* d_out, int out_size, void* d_ws, size_t ws_size,
                              hipStream_t stream)
{
    const float* feats = (const float*)d_in[0];
    float* out = (float*)d_out;
    float* ws  = (float*)d_ws;

    hipMemsetAsync(d_ws, 0, NSH * 4096 * sizeof(float), stream);
    cl_main<<<dim3(200), dim3(1024), 0, stream>>>(feats, ws);
    cl_final<<<dim3(1), dim3(1024), 0, stream>>>(ws, out);
}

// Round 8
// 102.844 us; speedup vs baseline: 1.4419x; 1.4419x over previous
//
#include <hip/hip_runtime.h>

typedef __attribute__((ext_vector_type(8))) __bf16 bf16x8;
typedef __attribute__((ext_vector_type(16))) float f32x16;
typedef unsigned long long u64;

#define KC 128             // k-floats per chunk
#define NCHUNK 16          // 2048 / 128
#define NSH 16             // dmat atomic shards
#define OFF_REC 65536      // float offset of per-t records, after dshard[16][4096]
#define RECSZ 8192         // per-t record: NN[4096] | AA[4096]

__device__ __forceinline__ ushort4 pack_bf16x4(float4 v) {
    union { ushort4 u; __bf16 b[4]; } p;
    p.b[0] = (__bf16)v.x; p.b[1] = (__bf16)v.y;
    p.b[2] = (__bf16)v.z; p.b[3] = (__bf16)v.w;
    return p.u;
}

// grid 200 (one block per t) x 256 threads (4 waves).
// Wave w owns 32x32 tile (it=w>>1, jt=w&1) of D=N.A^T, NN, AA via mfma_32x32x16.
// LDS is FRAGMENT-LINEAR: each (band, ks) fragment is a contiguous 1KB block in
// MFMA lane order -> ds_read_b128 is a perfect linear sweep (zero bank conflicts).
__global__ __launch_bounds__(256, 1) void cl_main(const float* __restrict__ feats,
                                                  float* __restrict__ ws)
{
    const int t   = blockIdx.x;          // 0..199
    const int tid = threadIdx.x;
    const int w   = tid >> 6;            // wave 0..3 == band (rows w*32..w*32+31)
    const int l   = tid & 63;
    const int it  = w >> 1, jt = w & 1;
    const int c31 = l & 31, h = l >> 5;

    // 4 bands x 8 ks x 512 ushorts (1KB frag) = 32 KB
    __shared__ __align__(16) unsigned short lds[16384];
    __shared__ float n2s[64], a2s[64];

    const size_t kbase = (size_t)t * 2048;

    f32x16 accD = {0}, accNN = {0}, accAA = {0};

    // write-side indexing for staging (lane l holds k = (l&31)*4 .. +3 of a row)
    const int wks = (l & 31) >> 2;               // frag ks 0..7
    const int wkh = ((l & 31) >> 1) & 1;         // k-half within frag
    const int we  = (l & 1) * 4;                 // ushort offset within 16B slot

    float4 st[16];   // staged chunk: 32 rows of band w, 2 rows per wave-instr

#define LOADCH(c)                                                            \
    {                                                                        \
        _Pragma("unroll")                                                    \
        for (int j = 0; j < 16; ++j) {                                       \
            const int row = w*32 + 2*j + h;                                  \
            st[j] = *(const float4*)(feats + (size_t)row * 409600 + kbase    \
                                     + (c)*KC + (l & 31)*4);                 \
        }                                                                    \
    }

#define WRITECH()                                                            \
    {                                                                        \
        _Pragma("unroll")                                                    \
        for (int j = 0; j < 16; ++j) {                                       \
            const int r = 2*j + h;                   /* row within band */   \
            const int slot = (wkh << 5) | r;                                 \
            const int us = w*4096 + wks*512 + ((slot ^ wks) << 3) + we;      \
            *(ushort4*)&lds[us] = pack_bf16x4(st[j]);                        \
        }                                                                    \
    }

#define FRAG(band, ks) (*(const bf16x8*)&lds[(band)*4096 + (ks)*512 + ((l ^ (ks)) << 3)])

#define MFMACH()                                                             \
    {                                                                        \
        _Pragma("unroll")                                                    \
        for (int ks = 0; ks < 8; ++ks) {                                     \
            bf16x8 aN = FRAG(it,     ks);                                    \
            bf16x8 aA = FRAG(2 + it, ks);                                    \
            bf16x8 bN = FRAG(jt,     ks);                                    \
            bf16x8 bA = FRAG(2 + jt, ks);                                    \
            accD  = __builtin_amdgcn_mfma_f32_32x32x16_bf16(aN, bA, accD,  0, 0, 0); \
            accNN = __builtin_amdgcn_mfma_f32_32x32x16_bf16(aN, bN, accNN, 0, 0, 0); \
            accAA = __builtin_amdgcn_mfma_f32_32x32x16_bf16(aA, bA, accAA, 0, 0, 0); \
        }                                                                    \
    }

    LOADCH(0)
    #pragma unroll 1
    for (int c = 0; c < NCHUNK; ++c) {
        WRITECH()                       // waits on this chunk's loads
        __syncthreads();
        if (c + 1 < NCHUNK) LOADCH(c + 1)   // in flight across the MFMA phase
        MFMACH()
        __syncthreads();
    }

    // n2/a2 from Gram diagonals (waves with it==jt); static reg indexing
    if (it == jt) {
        #pragma unroll
        for (int reg = 0; reg < 16; ++reg) {
            const int rowf = (reg & 3) + 8*(reg >> 2) + 4*h;
            if (rowf == c31) {
                n2s[it*32 + c31] = accNN[reg];
                a2s[it*32 + c31] = accAA[reg];
            }
        }
    }
    __syncthreads();

    // epilogue: hinge -> sharded dmat atomics; NN/AA -> exclusive per-t record
    const int sh = (t & (NSH - 1)) * 4096;
    float* rec = ws + OFF_REC + (size_t)t * RECSZ;
    #pragma unroll
    for (int reg = 0; reg < 16; ++reg) {
        const int i  = it*32 + (reg & 3) + 8*(reg >> 2) + 4*h;
        const int j  = jt*32 + c31;
        const int ij = i*64 + j;
        float dist2 = fmaxf(n2s[i] + a2s[j] - 2.f * accD[reg], 0.f);
        float v = fmaxf(200.f - sqrtf(dist2), 0.f);
        atomicAdd(&ws[sh + ij], v * v * 0.005f);   // 1/200
        rec[ij]        = accNN[reg];
        rec[4096 + ij] = accAA[reg];
    }
#undef LOADCH
#undef WRITECH
#undef FRAG
#undef MFMACH
}

__global__ __launch_bounds__(1024) void cl_final(const float* __restrict__ ws,
                                                 float* __restrict__ out)
{
    const int tid = threadIdx.x;
    __shared__ u64   wmin[16];
    __shared__ int   sIdx;
    __shared__ float sDmin;
    __shared__ float sG[16][64], sA[16][64], sRn[16][64], sRa[16][64];

    // argmin over shard-summed dmat, first-occurrence tie-break via packed key
    u64 best = ~0ull;
    #pragma unroll
    for (int u = 0; u < 4; ++u) {
        const int ij = u*1024 + tid;
        float s = 0.f;
        #pragma unroll
        for (int sh = 0; sh < NSH; ++sh) s += ws[sh*4096 + ij];
        u64 key = ((u64)__float_as_uint(s) << 12) | (unsigned)ij;   // s>=0: order-preserving
        best = key < best ? key : best;
    }
    #pragma unroll
    for (int off = 32; off > 0; off >>= 1) {
        u64 o = __shfl_xor(best, off);
        best = o < best ? o : best;
    }
    if ((tid & 63) == 0) wmin[tid >> 6] = best;
    __syncthreads();
    if (tid == 0) {
        u64 m = wmin[0];
        for (int k = 1; k < 16; ++k) m = wmin[k] < m ? wmin[k] : m;
        sIdx  = (int)(m & 0xFFF);
        sDmin = __uint_as_float((unsigned)(m >> 12));
    }
    __syncthreads();
    const int idx = sIdx;
    const int mn = idx >> 6;
    const int ma = idx & 63;

    // Gram columns at (mn, ma) + diagonals, summed over t (16 t-phases)
    const int g = tid >> 6;
    const int i = tid & 63;
    float gcn = 0.f, gca = 0.f, rn = 0.f, ra = 0.f;
    for (int t = g; t < 200; t += 16) {
        const float* rec = ws + OFF_REC + (size_t)t * RECSZ;
        gcn += rec[i*64 + mn];
        gca += rec[4096 + i*64 + ma];
        rn  += rec[i*65];          // NN diag -> Rn[i]
        ra  += rec[4096 + i*65];   // AA diag -> Ra[i]
    }
    sG[g][i] = gcn; sA[g][i] = gca; sRn[g][i] = rn; sRa[g][i] = ra;
    __syncthreads();

    if (tid < 64) {   // wave 0
        float fgn = 0.f, fga = 0.f, frn = 0.f, fra = 0.f;
        #pragma unroll
        for (int g2 = 0; g2 < 16; ++g2) {
            fgn += sG[g2][tid];  fga += sA[g2][tid];
            frn += sRn[g2][tid]; fra += sRa[g2][tid];
        }
        const float rnm = __shfl(frn, mn);
        const float ram = __shfl(fra, ma);
        float tn = (tid != mn) ? (frn + rnm - 2.f * fgn) : 0.f;
        float ta = (tid != ma) ? (fra + ram - 2.f * fga) : 0.f;
        float s = tn + ta;
        #pragma unroll
        for (int off = 32; off > 0; off >>= 1) s += __shfl_xor(s, off);
        if (tid == 0)
            out[0] = 0.001f * sDmin + s * (1.f / 12800.f);   // /(200*64)
    }
}

extern "C" void kernel_launch(void* const* d_in, const int* in_sizes, int n_in,
                              void* d_out, int out_size, void* d_ws, size_t ws_size,
                              hipStream_t stream)
{
    const float* feats = (const float*)d_in[0];
    float* out = (float*)d_out;
    float* ws  = (float*)d_ws;

    hipMemsetAsync(d_ws, 0, NSH * 4096 * sizeof(float), stream);
    cl_main<<<dim3(200), dim3(256), 0, stream>>>(feats, ws);
    cl_final<<<dim3(1), dim3(1024), 0, stream>>>(ws, out);
}

// Round 9
// 52.073 us; speedup vs baseline: 2.8478x; 1.9750x over previous
//
#include <hip/hip_runtime.h>

typedef __attribute__((ext_vector_type(8))) __bf16 bf16x8;
typedef __attribute__((ext_vector_type(4))) float f32x4;
typedef unsigned long long u64;

#define NCHUNK 32          // K chunks of 64
#define KC 64
#define NSH 16             // shards for cross-block accumulation
#define OFF_RN 65536       // RnSh[16][64]
#define OFF_RA 66560       // RaSh[16][64]
#define OFF_REC 67584      // per-t records: NN[4096] | AA[4096]
#define RECSZ 8192

__device__ __forceinline__ unsigned short f2bf(float x) {
    unsigned u = __float_as_uint(x);
    u += 0x7FFFu + ((u >> 16) & 1u);   // round-to-nearest-even
    return (unsigned short)(u >> 16);
}

// grid 200 (one block per t) x 512 threads (8 waves = 2/SIMD).
// R1's proven LDS swizzle + MFMA mapping; double-buffered LDS with chunk
// ownership alternating between the two half-blocks: owner of chunk c issues
// its loads one full chunk early and writes buf[c&1] while everyone computes
// from the other buffer. One barrier per chunk.
__global__ __launch_bounds__(512, 2) void cl_main(const float* __restrict__ feats,
                                                  float* __restrict__ ws)
{
    const int t   = blockIdx.x;          // 0..199
    const int tid = threadIdx.x;         // 0..511
    const int own = tid >> 8;            // staging half 0/1
    const int ht  = tid & 255;
    const int row = ht >> 2;             // loader row 0..63
    const int q   = ht & 3;              // 4 loader lanes per row
    const int w   = tid >> 6;            // wave 0..7
    const int r16 = tid & 15;
    const int kg  = (tid & 63) >> 4;
    const int it  = w >> 1;              // output row-tile 0..3
    const int jp  = w & 1;               // j-tile pair: {2jp, 2jp+1}

    __shared__ __align__(16) unsigned short lN[2][64][64];   // 16 KB
    __shared__ __align__(16) unsigned short lA[2][64][64];   // 16 KB
    __shared__ float n2s[64], a2s[64];

    const float* gN = feats + (size_t)row        * 409600 + (size_t)t * 2048;
    const float* gA = feats + (size_t)(64 + row) * 409600 + (size_t)t * 2048;

    f32x4 accD[2], accNN[2], accAA[2];
    const f32x4 zero = {0.f, 0.f, 0.f, 0.f};
    #pragma unroll
    for (int j = 0; j < 2; ++j) { accD[j] = zero; accNN[j] = zero; accAA[j] = zero; }

    const int swz  = (row & 7) << 3;     // write-side XOR swizzle (R1-proven)
    const int rswz = (r16 & 7) << 3;     // read-side

    float4 rN[4], rA[4];                 // staging regs (each half uses alternately)

#define LOAD_CH(c)                                                     \
    {                                                                  \
        _Pragma("unroll")                                              \
        for (int s = 0; s < 4; ++s) {                                  \
            const int k = 4 * q + 16 * s;                              \
            rN[s] = *(const float4*)(gN + (c) * KC + k);               \
            rA[s] = *(const float4*)(gA + (c) * KC + k);               \
        }                                                              \
    }

#define WRITE_CH(buf)                                                  \
    {                                                                  \
        _Pragma("unroll")                                              \
        for (int s = 0; s < 4; ++s) {                                  \
            const int k = 4 * q + 16 * s;                              \
            ushort4 pn, pa;                                            \
            pn.x=f2bf(rN[s].x); pn.y=f2bf(rN[s].y);                    \
            pn.z=f2bf(rN[s].z); pn.w=f2bf(rN[s].w);                    \
            pa.x=f2bf(rA[s].x); pa.y=f2bf(rA[s].y);                    \
            pa.z=f2bf(rA[s].z); pa.w=f2bf(rA[s].w);                    \
            *(ushort4*)&lN[buf][row][k ^ swz] = pn;                    \
            *(ushort4*)&lA[buf][row][k ^ swz] = pa;                    \
        }                                                              \
    }

#define MFMA_CH(buf)                                                   \
    {                                                                  \
        _Pragma("unroll")                                              \
        for (int ks = 0; ks < 2; ++ks) {                               \
            const int kb = (ks*32 + kg*8) ^ rswz;                      \
            bf16x8 aN  = *(const bf16x8*)&lN[buf][it*16 + r16][kb];    \
            bf16x8 aA  = *(const bf16x8*)&lA[buf][it*16 + r16][kb];    \
            bf16x8 bN0 = *(const bf16x8*)&lN[buf][(2*jp)*16 + r16][kb];      \
            bf16x8 bA0 = *(const bf16x8*)&lA[buf][(2*jp)*16 + r16][kb];      \
            bf16x8 bN1 = *(const bf16x8*)&lN[buf][(2*jp+1)*16 + r16][kb];    \
            bf16x8 bA1 = *(const bf16x8*)&lA[buf][(2*jp+1)*16 + r16][kb];    \
            accD[0]  = __builtin_amdgcn_mfma_f32_16x16x32_bf16(aN, bA0, accD[0],  0,0,0); \
            accNN[0] = __builtin_amdgcn_mfma_f32_16x16x32_bf16(aN, bN0, accNN[0], 0,0,0); \
            accAA[0] = __builtin_amdgcn_mfma_f32_16x16x32_bf16(aA, bA0, accAA[0], 0,0,0); \
            accD[1]  = __builtin_amdgcn_mfma_f32_16x16x32_bf16(aN, bA1, accD[1],  0,0,0); \
            accNN[1] = __builtin_amdgcn_mfma_f32_16x16x32_bf16(aN, bN1, accNN[1], 0,0,0); \
            accAA[1] = __builtin_amdgcn_mfma_f32_16x16x32_bf16(aA, bA1, accAA[1], 0,0,0); \
        }                                                              \
    }

    if (own == 0) LOAD_CH(0)             // prologue: half0 issues chunk 0

    #pragma unroll 1
    for (int c = 0; c < NCHUNK; ++c) {
        if (own == ((c + 1) & 1) && c + 1 < NCHUNK) LOAD_CH(c + 1)  // issue early
        if (own == (c & 1)) WRITE_CH(c & 1)   // loads from iter c-1 have a full chunk of cover
        __syncthreads();                      // buf[c&1] ready; buf[1-(c&1)] free for next write
        MFMA_CH(c & 1)
    }

    // n2/a2 from Gram diagonals (waves whose j-pair contains it); static acc index
    if (it == 2*jp && kg == (r16 >> 2)) {
        n2s[it*16 + r16] = accNN[0][r16 & 3];
        a2s[it*16 + r16] = accAA[0][r16 & 3];
    } else if (it == 2*jp + 1 && kg == (r16 >> 2)) {
        n2s[it*16 + r16] = accNN[1][r16 & 3];
        a2s[it*16 + r16] = accAA[1][r16 & 3];
    }
    __syncthreads();

    // epilogue: hinge -> sharded dmat atomics; NN/AA -> exclusive per-t record
    const int sh = (t & (NSH - 1)) * 4096;
    float* rec = ws + OFF_REC + (size_t)t * RECSZ;
    #pragma unroll
    for (int jx = 0; jx < 2; ++jx) {
        const int j = (2*jp + jx)*16 + r16;
        const float a2v = a2s[j];
        #pragma unroll
        for (int r = 0; r < 4; ++r) {
            const int i  = it*16 + kg*4 + r;
            const int ij = i*64 + j;
            float dist2 = fmaxf(n2s[i] + a2v - 2.f * accD[jx][r], 0.f);
            float v = fmaxf(200.f - sqrtf(dist2), 0.f);
            atomicAdd(&ws[sh + ij], v * v * 0.005f);   // 1/200
            rec[ij]        = accNN[jx][r];
            rec[4096 + ij] = accAA[jx][r];
        }
    }
    // diagonals -> sharded Rn/Ra (removes all strided reads from cl_final)
    if (tid < 64)       atomicAdd(&ws[OFF_RN + (t & 15)*64 + tid],      n2s[tid]);
    else if (tid < 128) atomicAdd(&ws[OFF_RA + (t & 15)*64 + (tid-64)], a2s[tid-64]);
#undef LOAD_CH
#undef WRITE_CH
#undef MFMA_CH
}

__global__ __launch_bounds__(1024) void cl_final(const float* __restrict__ ws,
                                                 float* __restrict__ out)
{
    const int tid = threadIdx.x;
    __shared__ u64   wmin[16];
    __shared__ int   sIdx;
    __shared__ float sDmin;
    __shared__ float sG[16][64], sA[16][64];

    // argmin over shard-summed dmat, first-occurrence tie-break via packed key
    u64 best = ~0ull;
    #pragma unroll
    for (int u = 0; u < 4; ++u) {
        const int ij = u*1024 + tid;
        float s = 0.f;
        #pragma unroll
        for (int sh = 0; sh < NSH; ++sh) s += ws[sh*4096 + ij];
        u64 key = ((u64)__float_as_uint(s) << 12) | (unsigned)ij;   // s>=0: order-preserving
        best = key < best ? key : best;
    }
    #pragma unroll
    for (int off = 32; off > 0; off >>= 1) {
        u64 o = __shfl_xor(best, off);
        best = o < best ? o : best;
    }
    if ((tid & 63) == 0) wmin[tid >> 6] = best;
    __syncthreads();
    if (tid == 0) {
        u64 m = wmin[0];
        for (int k = 1; k < 16; ++k) m = wmin[k] < m ? wmin[k] : m;
        sIdx  = (int)(m & 0xFFF);
        sDmin = __uint_as_float((unsigned)(m >> 12));
    }
    __syncthreads();
    const int idx = sIdx;
    const int mn = idx >> 6;
    const int ma = idx & 63;

    // NN/AA are symmetric: column mn == row mn -> contiguous 256B reads per t
    const int g = tid >> 6;     // t-phase 0..15
    const int i = tid & 63;
    float gcn = 0.f, gca = 0.f;
    for (int t = g; t < 200; t += 16) {
        const float* rec = ws + OFF_REC + (size_t)t * RECSZ;
        gcn += rec[mn*64 + i];
        gca += rec[4096 + ma*64 + i];
    }
    sG[g][i] = gcn; sA[g][i] = gca;
    __syncthreads();

    if (tid < 64) {   // wave 0
        float fgn = 0.f, fga = 0.f, frn = 0.f, fra = 0.f;
        #pragma unroll
        for (int g2 = 0; g2 < 16; ++g2) { fgn += sG[g2][tid]; fga += sA[g2][tid]; }
        #pragma unroll
        for (int sh = 0; sh < NSH; ++sh) {
            frn += ws[OFF_RN + sh*64 + tid];
            fra += ws[OFF_RA + sh*64 + tid];
        }
        const float rnm = __shfl(frn, mn);
        const float ram = __shfl(fra, ma);
        float tn = (tid != mn) ? (frn + rnm - 2.f * fgn) : 0.f;
        float ta = (tid != ma) ? (fra + ram - 2.f * fga) : 0.f;
        float s = tn + ta;
        #pragma unroll
        for (int off = 32; off > 0; off >>= 1) s += __shfl_xor(s, off);
        if (tid == 0)
            out[0] = 0.001f * sDmin + s * (1.f / 12800.f);   // /(200*64)
    }
}

extern "C" void kernel_launch(void* const* d_in, const int* in_sizes, int n_in,
                              void* d_out, int out_size, void* d_ws, size_t ws_size,
                              hipStream_t stream)
{
    const float* feats = (const float*)d_in[0];
    float* out = (float*)d_out;
    float* ws  = (float*)d_ws;

    hipMemsetAsync(d_ws, 0, OFF_REC * sizeof(float), stream);
    cl_main<<<dim3(200), dim3(512), 0, stream>>>(feats, ws);
    cl_final<<<dim3(1), dim3(1024), 0, stream>>>(ws, out);
}